// Round 1
// baseline (467.963 us; speedup 1.0000x reference)
//
#include <hip/hip_runtime.h>

// LocallyConnected2D: y[n,h,w] = relu(sum_{i,j} x[n,h+i,w+j]*W[h,w,i,j] + b[h,w])
// N=64 (== wavefront), x: 64x512x512 f32, W: 504x504x9x9, b: 504x504, out: 64x504x504
//
// Design: lane = batch index n  ->  weights/bias are wave-uniform (scalar path).
// Block = 4 waves, tile = 8 out-rows x 8 out-cols x all 64 n.
// x tile staged in LDS as [row][colgrp4][n][4 floats] = 16*4*64*16 B = 64 KB,
// conflict-free ds_read_b128 / ds_write_b128 pattern (lane-consecutive 16B).
// Each wave computes 2 output rows (10 shared input rows -> x-register reuse).

#define H_IN 512
#define W_IN 512
#define H_OUT 504
#define W_OUT 504
#define W_T 8
#define H_T 8

__launch_bounds__(256, 2)
__global__ void lc2d_kernel(const float* __restrict__ x,
                            const float* __restrict__ weight,
                            const float* __restrict__ bias,
                            float* __restrict__ out) {
    // LDS: [row 0..15][cgrp 0..3][n 0..63][4 floats]  (floats)
    __shared__ float tile[16 * 4 * 64 * 4];   // 64 KB

    const int t  = threadIdx.x;
    const int h0 = blockIdx.y * H_T;
    const int w0 = blockIdx.x * W_T;

    // ---- stage x tile: rows h0..h0+15, cols w0..w0+15, all n ----
    // thread t owns (n = t>>2, cgrp = t&3), iterates rows 0..15.
    {
        const int n    = t >> 2;
        const int cgrp = t & 3;
        const float* gsrc = x + n * (H_IN * W_IN) + h0 * W_IN + w0 + cgrp * 4;
        float* ldst = &tile[cgrp * 256 + n * 4];
        #pragma unroll
        for (int row = 0; row < 16; ++row) {
            const float4 v = *reinterpret_cast<const float4*>(gsrc + row * W_IN);
            *reinterpret_cast<float4*>(ldst + row * 1024) = v;
        }
    }
    __syncthreads();

    const int wv   = __builtin_amdgcn_readfirstlane(t >> 6);  // wave id 0..3
    const int lane = t & 63;                                   // batch index n
    const int ha   = h0 + 2 * wv;                              // first of 2 output rows

    // accumulators initialized with bias (wave-uniform scalar loads)
    float acc0[W_T], acc1[W_T];
    const float* bptr = bias + ha * W_OUT + w0;
    #pragma unroll
    for (int k = 0; k < W_T; ++k) {
        acc0[k] = bptr[k];
        acc1[k] = bptr[W_OUT + k];
    }

    const float* wbase = weight + (ha * W_OUT + w0) * 81;      // taps of (ha, w0..)
    const int rowbase = 2 * wv;                                 // local LDS row offset

    // input rows r = 0..9 relative to ha; row r feeds:
    //   out row ha   with tap-row i = r    (valid r 0..8)
    //   out row ha+1 with tap-row i = r-1  (valid r 1..9)
    for (int r = 0; r < 10; ++r) {
        float xr[16];
        const int lrow = rowbase + r;
        #pragma unroll
        for (int c = 0; c < 4; ++c) {
            const float4 v = *reinterpret_cast<const float4*>(
                &tile[lrow * 1024 + c * 256 + lane * 4]);
            xr[4 * c + 0] = v.x; xr[4 * c + 1] = v.y;
            xr[4 * c + 2] = v.z; xr[4 * c + 3] = v.w;
        }
        if (r < 9) {
            const float* wa = wbase + r * 9;
            #pragma unroll
            for (int k = 0; k < W_T; ++k)
                #pragma unroll
                for (int j = 0; j < 9; ++j)
                    acc0[k] = fmaf(wa[k * 81 + j], xr[k + j], acc0[k]);
        }
        if (r > 0) {
            const float* wb = wbase + 81 * W_OUT + (r - 1) * 9;
            #pragma unroll
            for (int k = 0; k < W_T; ++k)
                #pragma unroll
                for (int j = 0; j < 9; ++j)
                    acc1[k] = fmaf(wb[k * 81 + j], xr[k + j], acc1[k]);
        }
    }

    // ---- epilogue: ReLU + store (per-lane 2 rows x 8 floats, 16B-aligned) ----
    float* o0 = out + (size_t)lane * (H_OUT * W_OUT) + ha * W_OUT + w0;
    float4 s;
    s.x = fmaxf(acc0[0], 0.f); s.y = fmaxf(acc0[1], 0.f);
    s.z = fmaxf(acc0[2], 0.f); s.w = fmaxf(acc0[3], 0.f);
    *reinterpret_cast<float4*>(o0) = s;
    s.x = fmaxf(acc0[4], 0.f); s.y = fmaxf(acc0[5], 0.f);
    s.z = fmaxf(acc0[6], 0.f); s.w = fmaxf(acc0[7], 0.f);
    *reinterpret_cast<float4*>(o0 + 4) = s;
    s.x = fmaxf(acc1[0], 0.f); s.y = fmaxf(acc1[1], 0.f);
    s.z = fmaxf(acc1[2], 0.f); s.w = fmaxf(acc1[3], 0.f);
    *reinterpret_cast<float4*>(o0 + W_OUT) = s;
    s.x = fmaxf(acc1[4], 0.f); s.y = fmaxf(acc1[5], 0.f);
    s.z = fmaxf(acc1[6], 0.f); s.w = fmaxf(acc1[7], 0.f);
    *reinterpret_cast<float4*>(o0 + W_OUT + 4) = s;
}

extern "C" void kernel_launch(void* const* d_in, const int* in_sizes, int n_in,
                              void* d_out, int out_size, void* d_ws, size_t ws_size,
                              hipStream_t stream) {
    const float* x      = (const float*)d_in[0];
    const float* weight = (const float*)d_in[1];
    const float* bias   = (const float*)d_in[2];
    float* out          = (float*)d_out;

    dim3 grid(W_OUT / W_T, H_OUT / H_T);   // 63 x 63
    dim3 block(256);
    lc2d_kernel<<<grid, block, 0, stream>>>(x, weight, bias, out);
}